// Round 2
// baseline (225.564 us; speedup 1.0000x reference)
//
#include <hip/hip_runtime.h>
#include <stdint.h>

#define D_MODEL 768
#define E3      2304
#define NCTX    2048
#define NH      12
#define HD      64
#define MROWS   4096  // 2*2048
#define NHTOT   24    // 2*12

typedef __attribute__((ext_vector_type(8))) short short8;   // 8 bf16 — MFMA x32 A/B frag
typedef __attribute__((ext_vector_type(4))) short bf16x4;   // 4 bf16 — MFMA x16 A/B frag
typedef __attribute__((ext_vector_type(4))) float f32x4;    // MFMA C/D frag

typedef __attribute__((address_space(3))) uint32_t lds_u32;
typedef __attribute__((address_space(1))) uint32_t glob_u32;

__device__ __forceinline__ void async_copy16(const void* g, void* l) {
    __builtin_amdgcn_global_load_lds((const glob_u32*)(uintptr_t)g,
                                     (lds_u32*)(uint32_t)(uintptr_t)l, 16, 0, 0);
}

__device__ __forceinline__ unsigned short f2bf(float f) {  // RNE fp32->bf16
    uint32_t u = __builtin_bit_cast(uint32_t, f);
    u += 0x7fffu + ((u >> 16) & 1u);
    return (unsigned short)(u >> 16);
}

__device__ __forceinline__ float fast_exp2(float x) {
#if __has_builtin(__builtin_amdgcn_exp2f)
    return __builtin_amdgcn_exp2f(x);
#else
    return __expf(x * 0.6931471805599453f);
#endif
}

#if __has_builtin(__builtin_amdgcn_mfma_f32_16x16x16bf16_1k)
#define HAVE_MFMA16 1
#else
#define HAVE_MFMA16 0
#endif

// ---------------- fused cast fp32 -> bf16 (x and W in one dispatch) ----------------
__global__ __launch_bounds__(256) void cast2_bf16_kernel(const float* __restrict__ a,
                                                         unsigned short* __restrict__ oa,
                                                         int na4,
                                                         const float* __restrict__ b,
                                                         unsigned short* __restrict__ ob) {
    int i = blockIdx.x * blockDim.x + threadIdx.x;
    const float4* src;
    ushort4* dst;
    int idx;
    if (i < na4) { src = (const float4*)a; dst = (ushort4*)oa; idx = i; }
    else         { src = (const float4*)b; dst = (ushort4*)ob; idx = i - na4; }
    float4 v = src[idx];
    ushort4 o;
    o.x = f2bf(v.x); o.y = f2bf(v.y); o.z = f2bf(v.z); o.w = f2bf(v.w);
    dst[idx] = o;
}

// ---------------- QKV GEMM, BK=64 (unchanged — at 128^2 structure ceiling) ----------------
// Outputs (all bf16):
//  Q -> Zq[4096][768], scaled by log2e/sqrt(768)
//  K -> Kb blocked: per (nh,kb64): elem (((ks*4+ct)*4+quadd)*16+l15k)*8+e
//       where d=ks*32+quadd*8+e, key%64=ct*16+l15k  (lane-linear for attn frag reads)
//  V -> Vb blocked: per (nh,kb64): elem (((ct*4+dt)*4+quadv)*16+l15d)*4+e
//       where key%64=ct*16+quadv*4+e, d=dt*16+l15d
__global__ __launch_bounds__(256) void qkv_gemm(const unsigned short* __restrict__ A,
                                                const unsigned short* __restrict__ B,
                                                const float* __restrict__ bias,
                                                unsigned short* __restrict__ Zq,
                                                unsigned short* __restrict__ Kb,
                                                unsigned short* __restrict__ Vb) {
    __shared__ __attribute__((aligned(16))) unsigned short sA[128 * 64];
    __shared__ __attribute__((aligned(16))) unsigned short sB[128 * 64];

    const int tid  = threadIdx.x;
    const int wave = tid >> 6;
    const int lane = tid & 63;
    const int quad = lane >> 4;
    const int l15  = lane & 15;
    const int wm   = (wave >> 1) << 6;
    const int wn   = (wave & 1) << 6;
    const int row0 = blockIdx.y * 128;
    const int col0 = blockIdx.x * 128;

    const int srow   = lane >> 3;        // 0..7
    const int schunk = (lane & 7) * 8;   // elem offset within 64-elem row

    f32x4 acc[4][4] = {};

    for (int k0 = 0; k0 < D_MODEL; k0 += 64) {
        __syncthreads();
#pragma unroll
        for (int c = 0; c < 4; ++c) {    // 8-row chunks; 4 per wave per matrix
            const int rbase = wave * 32 + c * 8;
            async_copy16(A + (size_t)(row0 + rbase + srow) * D_MODEL + k0 + schunk, &sA[rbase * 64]);
            async_copy16(B + (size_t)(col0 + rbase + srow) * D_MODEL + k0 + schunk, &sB[rbase * 64]);
        }
        __syncthreads();

#pragma unroll
        for (int ks = 0; ks < 2; ++ks) {
            short8 aF[4], bF[4];
#pragma unroll
            for (int i = 0; i < 4; ++i)
                aF[i] = *(const short8*)&sA[(wm + i * 16 + l15) * 64 + ks * 32 + quad * 8];
#pragma unroll
            for (int i = 0; i < 4; ++i)
                bF[i] = *(const short8*)&sB[(wn + i * 16 + l15) * 64 + ks * 32 + quad * 8];
#pragma unroll
            for (int i = 0; i < 4; ++i)
#pragma unroll
                for (int j = 0; j < 4; ++j)
                    acc[i][j] = __builtin_amdgcn_mfma_f32_16x16x32_bf16(aF[i], bF[j], acc[i][j], 0, 0, 0);
        }
    }

    // epilogue: C/D layout col=lane&15 (j dim), row=quad*4+reg (i dim)
    if (col0 < D_MODEL) {
        // ---- K -> Kb blocked ----
#pragma unroll
        for (int j = 0; j < 4; ++j) {
            const int col = col0 + wn + j * 16 + l15;
            const float bv = bias[col];
            const int h = col >> 6, d = col & 63;
            const int ks = d >> 5, quadd = (d >> 3) & 3, e = d & 7;
#pragma unroll
            for (int i = 0; i < 4; ++i) {
                const int row = row0 + wm + i * 16 + quad * 4;   // +r
                const int n = row >> 11;
                const int key = row & (NCTX - 1);
                const int kb = key >> 6;
                const int ct = i;                                 // key%64 = i*16 + quad*4 + r
                const size_t base = ((size_t)((n * NH + h) * 32 + kb)) * 4096
                                  + (((ks * 4 + ct) * 4 + quadd) * 16) * 8 + e;
#pragma unroll
                for (int r = 0; r < 4; ++r)
                    Kb[base + (size_t)(quad * 4 + r) * 8] = f2bf(acc[i][j][r] + bv);
            }
        }
    } else if (col0 < 2 * D_MODEL) {
        // ---- Q -> Zq (scaled) ----
        const float zscale = 0.036084391824351615f * 1.4426950408889634f;
#pragma unroll
        for (int j = 0; j < 4; ++j) {
            const int col = col0 - D_MODEL + wn + j * 16 + l15;
            const float bv = bias[col0 + wn + j * 16 + l15];
#pragma unroll
            for (int i = 0; i < 4; ++i) {
                const int row = row0 + wm + i * 16 + quad * 4;
#pragma unroll
                for (int r = 0; r < 4; ++r)
                    Zq[(size_t)(row + r) * D_MODEL + col] = f2bf((acc[i][j][r] + bv) * zscale);
            }
        }
    } else {
        // ---- V -> Vb blocked (ushort4 over r: e=key&3) ----
#pragma unroll
        for (int j = 0; j < 4; ++j) {
            const int col = col0 + wn + j * 16 + l15;
            const float bv = bias[col];
            const int ch = col - 2 * D_MODEL;
            const int h = ch >> 6, d = ch & 63;
            const int dt = d >> 4, l15d = d & 15;
#pragma unroll
            for (int i = 0; i < 4; ++i) {
                const int row = row0 + wm + i * 16 + quad * 4;    // key base, %4==0
                const int n = row >> 11;
                const int key = row & (NCTX - 1);
                const int kb = key >> 6;
                const int ct = i, quadv = quad;
                ushort4 w4;
                w4.x = f2bf(acc[i][j][0] + bv);
                w4.y = f2bf(acc[i][j][1] + bv);
                w4.z = f2bf(acc[i][j][2] + bv);
                w4.w = f2bf(acc[i][j][3] + bv);
                *(ushort4*)&Vb[((size_t)((n * NH + h) * 32 + kb)) * 4096
                               + (((ct * 4 + dt) * 4 + quadv) * 16 + l15d) * 4] = w4;
            }
        }
    }
}

// ---------------- flash attention: 1 wave/block, q32/wave, NO LDS, NO barriers ----------------
// K+V are only 12.6 MB (L2/L3-resident; FETCH_SIZE showed 9.2 MB) — LDS staging +
// per-iter __syncthreads + vmcnt(0) drain was the latency bottleneck (MfmaUtil 12.5%,
// VALUBusy 23%, all-low = latency-bound). Read K/V fragments DIRECTLY from the blocked
// global layouts (identical indices to the old LDS reads; staging was an identity copy):
//   kf: 8 x 16B/lane = 1KB coalesced bursts;  vf: 16 x 8B/lane = 512B bursts.
// kf register-double-buffered across kb (prefetch next); vf issued before softmax
// (~400 cyc of independent work before PV consumes them). Compiler emits COUNTED
// vmcnt for register loads — pipeline survives (no barrier drain anywhere).
// Grid swizzle: bid%8 -> XCD gets nh%8 == xcd -> 3 heads/XCD = 1.6 MB K+V < 4 MB L2.
// Heavy q-tiles dispatched first. 1536 waves = 6/CU.
__global__ __launch_bounds__(64) void attn_kernel(const unsigned short* __restrict__ Zq,
                                                  const unsigned short* __restrict__ Kb,
                                                  const unsigned short* __restrict__ Vb,
                                                  float* __restrict__ out) {
#if !HAVE_MFMA16
    __shared__ __attribute__((aligned(16))) unsigned short sP[16 * 72];
#endif
    const int lane = threadIdx.x & 63;
    const int quad = lane >> 4;
    const int l15  = lane & 15;
    const int b    = blockIdx.x;
    const int xcd  = b & 7;
    const int ii   = b >> 3;            // 0..191
    const int qt   = 63 - ii / 3;       // heavy-first q32-tile index within (n,h)
    const int nh   = (ii % 3) * 8 + xcd;
    const int n    = nh / NH;
    const int h    = nh - n * NH;
    const int kbmax = qt >> 1;          // last key64-block touching rows [qt*32, qt*32+31]

    const unsigned short* KbP = Kb + (size_t)(nh * 32) * 4096;
    const unsigned short* VbP = Vb + (size_t)(nh * 32) * 4096;

    // Q B-frags: lane holds Q[q = qt*32 + g*16 + l15][d = ks*32+quad*8..+7]
    const unsigned short* Qp = Zq + (size_t)(n * NCTX + qt * 32) * D_MODEL + h * HD;
    short8 qf[2][2];
#pragma unroll
    for (int g = 0; g < 2; ++g)
#pragma unroll
        for (int ks = 0; ks < 2; ++ks)
            qf[g][ks] = *(const short8*)&Qp[(size_t)(g * 16 + l15) * D_MODEL + ks * 32 + quad * 8];

    f32x4 o[2][4] = {};                 // [g][dt]: O[q=quad*4+r][d=dt*16+l15]
    float lsum[2] = {0.0f, 0.0f};       // partial row-sums for q=l15 per group

    // prologue: kf for kb=0
    short8 kf[2][2][4];                 // [buf][ks][ct]
#pragma unroll
    for (int ks = 0; ks < 2; ++ks)
#pragma unroll
        for (int ct = 0; ct < 4; ++ct)
            kf[0][ks][ct] = *(const short8*)&KbP[(ks * 4 + ct) * 512 + lane * 8];

    for (int kb = 0; kb <= kbmax; ++kb) {
        const int cur = kb & 1;

        // vf for this kb (needed soonest-after kf: issue first)
        const unsigned short* vp = VbP + (size_t)kb * 4096;
        bf16x4 vf[16];
#pragma unroll
        for (int c = 0; c < 16; ++c)
            vf[c] = *(const bf16x4*)&vp[c * 256 + lane * 4];

        // prefetch next kb's K frags into the other register buffer
        if (kb < kbmax) {
            const unsigned short* kp = KbP + (size_t)(kb + 1) * 4096;
#pragma unroll
            for (int ks = 0; ks < 2; ++ks)
#pragma unroll
                for (int ct = 0; ct < 4; ++ct)
                    kf[cur ^ 1][ks][ct] = *(const short8*)&kp[(ks * 4 + ct) * 512 + lane * 8];
        }

        const bool diag = (kb == kbmax);
#if HAVE_MFMA16
        bf16x4 pA[2][4];
#endif
#pragma unroll
        for (int g = 0; g < 2; ++g) {
            // S^T = K Q^T: lane holds S[q=l15][key = kb*64 + ct*16 + quad*4 + r]
            f32x4 s[4] = {};
            __builtin_amdgcn_s_setprio(1);
#pragma unroll
            for (int ct = 0; ct < 4; ++ct) {
                s[ct] = __builtin_amdgcn_mfma_f32_16x16x32_bf16(kf[cur][0][ct], qf[g][0], s[ct], 0, 0, 0);
                s[ct] = __builtin_amdgcn_mfma_f32_16x16x32_bf16(kf[cur][1][ct], qf[g][1], s[ct], 0, 0, 0);
            }
            __builtin_amdgcn_s_setprio(0);

            const int qg = qt * 32 + g * 16 + l15;
#pragma unroll
            for (int ct = 0; ct < 4; ++ct) {
                float pv[4];
#pragma unroll
                for (int r = 0; r < 4; ++r) {
                    const int key = kb * 64 + ct * 16 + quad * 4 + r;
                    float sv = s[ct][r];
                    if (diag && key > qg) sv = -INFINITY;
                    pv[r] = fast_exp2(sv);
                    lsum[g] += pv[r];
                }
#if HAVE_MFMA16
                pA[g][ct][0] = (short)f2bf(pv[0]); pA[g][ct][1] = (short)f2bf(pv[1]);
                pA[g][ct][2] = (short)f2bf(pv[2]); pA[g][ct][3] = (short)f2bf(pv[3]);
#else
                ushort4 w4;
                w4.x = f2bf(pv[0]); w4.y = f2bf(pv[1]); w4.z = f2bf(pv[2]); w4.w = f2bf(pv[3]);
                *(ushort4*)&sP[l15 * 72 + ct * 16 + quad * 4] = w4;
#endif
            }

#if !HAVE_MFMA16
            // fallback: sP round-trip + x32 (V consumed as x16-blocked pairs), per g
            const short8 pf0 = *(const short8*)&sP[l15 * 72 + quad * 8];
            const short8 pf1 = *(const short8*)&sP[l15 * 72 + 32 + quad * 8];
#pragma unroll
            for (int dt = 0; dt < 4; ++dt) {
                short8 vf0, vf1;
#pragma unroll
                for (int e = 0; e < 8; ++e) {
                    const int k0 = quad * 8 + e;          // within keys [0,32)
                    const int k1 = 32 + quad * 8 + e;
                    vf0[e] = (short)vp[(((k0 >> 4) * 4 + dt) * 4 + ((k0 >> 2) & 3)) * 64 + l15 * 4 + (k0 & 3)];
                    vf1[e] = (short)vp[(((k1 >> 4) * 4 + dt) * 4 + ((k1 >> 2) & 3)) * 64 + l15 * 4 + (k1 & 3)];
                }
                o[g][dt] = __builtin_amdgcn_mfma_f32_16x16x32_bf16(pf0, vf0, o[g][dt], 0, 0, 0);
                o[g][dt] = __builtin_amdgcn_mfma_f32_16x16x32_bf16(pf1, vf1, o[g][dt], 0, 0, 0);
            }
#endif
        }

#if HAVE_MFMA16
        // O += P V: each vf register feeds both g-MFMAs
        __builtin_amdgcn_s_setprio(1);
#pragma unroll
        for (int ct = 0; ct < 4; ++ct)
#pragma unroll
            for (int dt = 0; dt < 4; ++dt) {
                o[0][dt] = __builtin_amdgcn_mfma_f32_16x16x16bf16_1k(pA[0][ct], vf[ct * 4 + dt], o[0][dt], 0, 0, 0);
                o[1][dt] = __builtin_amdgcn_mfma_f32_16x16x16bf16_1k(pA[1][ct], vf[ct * 4 + dt], o[1][dt], 0, 0, 0);
            }
        __builtin_amdgcn_s_setprio(0);
#endif
    }

    // epilogue: per group, full row-sum for q=l15 (reduce across quads), normalize, store
#pragma unroll
    for (int g = 0; g < 2; ++g) {
        float l = lsum[g];
        l += __shfl_xor(l, 16);
        l += __shfl_xor(l, 32);
        const float linv = 1.0f / l;                      // valid for q=l15
#pragma unroll
        for (int r = 0; r < 4; ++r) {
            const float inv = __shfl(linv, quad * 4 + r); // source lane's l15 == output q row
            const size_t row = (size_t)n * NCTX + qt * 32 + g * 16 + quad * 4 + r;
#pragma unroll
            for (int dt = 0; dt < 4; ++dt)
                out[row * D_MODEL + h * HD + dt * 16 + l15] = o[g][dt][r] * inv;
        }
    }
}

extern "C" void kernel_launch(void* const* d_in, const int* in_sizes, int n_in,
                              void* d_out, int out_size, void* d_ws, size_t ws_size,
                              hipStream_t stream) {
    const float* x = (const float*)d_in[0];   // [2,2048,768]
    const float* W = (const float*)d_in[1];   // [2304,768]
    const float* b = (const float*)d_in[2];   // [2304]
    float* out = (float*)d_out;

    unsigned short* xb = (unsigned short*)d_ws;                    // 4096*768
    unsigned short* Wb = xb + (size_t)MROWS * D_MODEL;             // 2304*768
    unsigned short* Zq = Wb + (size_t)E3 * D_MODEL;                // 4096*768 (Q only)
    unsigned short* Kb = Zq + (size_t)MROWS * D_MODEL;             // 24*32*4096
    unsigned short* Vb = Kb + (size_t)NHTOT * 32 * 4096;           // 24*32*4096

    const int NA4 = MROWS * D_MODEL / 4;   // 786432 float4s (multiple of 256)
    const int NW4 = E3 * D_MODEL / 4;      // 442368 float4s
    cast2_bf16_kernel<<<dim3((NA4 + NW4) / 256), 256, 0, stream>>>(x, xb, NA4, W, Wb);
    qkv_gemm<<<dim3(E3 / 128, MROWS / 128), 256, 0, stream>>>(xb, Wb, b, Zq, Kb, Vb);
    attn_kernel<<<dim3(NHTOT * 64), 64, 0, stream>>>(Zq, Kb, Vb, out);
}

// Round 3
// 153.090 us; speedup vs baseline: 1.4734x; 1.4734x over previous
//
#include <hip/hip_runtime.h>
#include <stdint.h>

#define D_MODEL 768
#define E3      2304
#define NCTX    2048
#define NH      12
#define HD      64
#define MROWS   4096  // 2*2048
#define NHTOT   24    // 2*12

typedef __attribute__((ext_vector_type(8))) short short8;   // 8 bf16 — MFMA x32 A/B frag
typedef __attribute__((ext_vector_type(4))) short bf16x4;   // 4 bf16 — MFMA x16 A/B frag
typedef __attribute__((ext_vector_type(4))) float f32x4;    // MFMA C/D frag

typedef __attribute__((address_space(3))) uint32_t lds_u32;
typedef __attribute__((address_space(1))) uint32_t glob_u32;

__device__ __forceinline__ void async_copy16(const void* g, void* l) {
    __builtin_amdgcn_global_load_lds((const glob_u32*)(uintptr_t)g,
                                     (lds_u32*)(uint32_t)(uintptr_t)l, 16, 0, 0);
}

__device__ __forceinline__ unsigned short f2bf(float f) {  // RNE fp32->bf16
    uint32_t u = __builtin_bit_cast(uint32_t, f);
    u += 0x7fffu + ((u >> 16) & 1u);
    return (unsigned short)(u >> 16);
}

__device__ __forceinline__ float fast_exp2(float x) {
#if __has_builtin(__builtin_amdgcn_exp2f)
    return __builtin_amdgcn_exp2f(x);
#else
    return __expf(x * 0.6931471805599453f);
#endif
}

#if __has_builtin(__builtin_amdgcn_mfma_f32_16x16x16bf16_1k)
#define HAVE_MFMA16 1
#else
#define HAVE_MFMA16 0
#endif

// ---------------- fused cast fp32 -> bf16 (x and W in one dispatch) ----------------
__global__ __launch_bounds__(256) void cast2_bf16_kernel(const float* __restrict__ a,
                                                         unsigned short* __restrict__ oa,
                                                         int na4,
                                                         const float* __restrict__ b,
                                                         unsigned short* __restrict__ ob) {
    int i = blockIdx.x * blockDim.x + threadIdx.x;
    const float4* src;
    ushort4* dst;
    int idx;
    if (i < na4) { src = (const float4*)a; dst = (ushort4*)oa; idx = i; }
    else         { src = (const float4*)b; dst = (ushort4*)ob; idx = i - na4; }
    float4 v = src[idx];
    ushort4 o;
    o.x = f2bf(v.x); o.y = f2bf(v.y); o.z = f2bf(v.z); o.w = f2bf(v.w);
    dst[idx] = o;
}

// ---------------- QKV GEMM, BK=64 (unchanged — at 128^2 structure ceiling) ----------------
// Outputs (all bf16):
//  Q -> Zq[4096][768], scaled by log2e/sqrt(768)
//  K -> Kb blocked: per (nh,kb64): elem (((ks*4+ct)*4+quadd)*16+l15k)*8+e
//       where d=ks*32+quadd*8+e, key%64=ct*16+l15k  (lane-linear for attn LDS frags)
//  V -> Vb blocked: per (nh,kb64): elem (((ct*4+dt)*4+quadv)*16+l15d)*4+e
//       where key%64=ct*16+quadv*4+e, d=dt*16+l15d
__global__ __launch_bounds__(256) void qkv_gemm(const unsigned short* __restrict__ A,
                                                const unsigned short* __restrict__ B,
                                                const float* __restrict__ bias,
                                                unsigned short* __restrict__ Zq,
                                                unsigned short* __restrict__ Kb,
                                                unsigned short* __restrict__ Vb) {
    __shared__ __attribute__((aligned(16))) unsigned short sA[128 * 64];
    __shared__ __attribute__((aligned(16))) unsigned short sB[128 * 64];

    const int tid  = threadIdx.x;
    const int wave = tid >> 6;
    const int lane = tid & 63;
    const int quad = lane >> 4;
    const int l15  = lane & 15;
    const int wm   = (wave >> 1) << 6;
    const int wn   = (wave & 1) << 6;
    const int row0 = blockIdx.y * 128;
    const int col0 = blockIdx.x * 128;

    const int srow   = lane >> 3;        // 0..7
    const int schunk = (lane & 7) * 8;   // elem offset within 64-elem row

    f32x4 acc[4][4] = {};

    for (int k0 = 0; k0 < D_MODEL; k0 += 64) {
        __syncthreads();
#pragma unroll
        for (int c = 0; c < 4; ++c) {    // 8-row chunks; 4 per wave per matrix
            const int rbase = wave * 32 + c * 8;
            async_copy16(A + (size_t)(row0 + rbase + srow) * D_MODEL + k0 + schunk, &sA[rbase * 64]);
            async_copy16(B + (size_t)(col0 + rbase + srow) * D_MODEL + k0 + schunk, &sB[rbase * 64]);
        }
        __syncthreads();

#pragma unroll
        for (int ks = 0; ks < 2; ++ks) {
            short8 aF[4], bF[4];
#pragma unroll
            for (int i = 0; i < 4; ++i)
                aF[i] = *(const short8*)&sA[(wm + i * 16 + l15) * 64 + ks * 32 + quad * 8];
#pragma unroll
            for (int i = 0; i < 4; ++i)
                bF[i] = *(const short8*)&sB[(wn + i * 16 + l15) * 64 + ks * 32 + quad * 8];
#pragma unroll
            for (int i = 0; i < 4; ++i)
#pragma unroll
                for (int j = 0; j < 4; ++j)
                    acc[i][j] = __builtin_amdgcn_mfma_f32_16x16x32_bf16(aF[i], bF[j], acc[i][j], 0, 0, 0);
        }
    }

    // epilogue: C/D layout col=lane&15 (j dim), row=quad*4+reg (i dim)
    if (col0 < D_MODEL) {
        // ---- K -> Kb blocked ----
#pragma unroll
        for (int j = 0; j < 4; ++j) {
            const int col = col0 + wn + j * 16 + l15;
            const float bv = bias[col];
            const int h = col >> 6, d = col & 63;
            const int ks = d >> 5, quadd = (d >> 3) & 3, e = d & 7;
#pragma unroll
            for (int i = 0; i < 4; ++i) {
                const int row = row0 + wm + i * 16 + quad * 4;   // +r
                const int n = row >> 11;
                const int key = row & (NCTX - 1);
                const int kb = key >> 6;
                const int ct = i;                                 // key%64 = i*16 + quad*4 + r
                const size_t base = ((size_t)((n * NH + h) * 32 + kb)) * 4096
                                  + (((ks * 4 + ct) * 4 + quadd) * 16) * 8 + e;
#pragma unroll
                for (int r = 0; r < 4; ++r)
                    Kb[base + (size_t)(quad * 4 + r) * 8] = f2bf(acc[i][j][r] + bv);
            }
        }
    } else if (col0 < 2 * D_MODEL) {
        // ---- Q -> Zq (scaled) ----
        const float zscale = 0.036084391824351615f * 1.4426950408889634f;
#pragma unroll
        for (int j = 0; j < 4; ++j) {
            const int col = col0 - D_MODEL + wn + j * 16 + l15;
            const float bv = bias[col0 + wn + j * 16 + l15];
#pragma unroll
            for (int i = 0; i < 4; ++i) {
                const int row = row0 + wm + i * 16 + quad * 4;
#pragma unroll
                for (int r = 0; r < 4; ++r)
                    Zq[(size_t)(row + r) * D_MODEL + col] = f2bf((acc[i][j][r] + bv) * zscale);
            }
        }
    } else {
        // ---- V -> Vb blocked (ushort4 over r: e=key&3) ----
#pragma unroll
        for (int j = 0; j < 4; ++j) {
            const int col = col0 + wn + j * 16 + l15;
            const float bv = bias[col];
            const int ch = col - 2 * D_MODEL;
            const int h = ch >> 6, d = ch & 63;
            const int dt = d >> 4, l15d = d & 15;
#pragma unroll
            for (int i = 0; i < 4; ++i) {
                const int row = row0 + wm + i * 16 + quad * 4;    // key base, %4==0
                const int n = row >> 11;
                const int key = row & (NCTX - 1);
                const int kb = key >> 6;
                const int ct = i, quadv = quad;
                ushort4 w4;
                w4.x = f2bf(acc[i][j][0] + bv);
                w4.y = f2bf(acc[i][j][1] + bv);
                w4.z = f2bf(acc[i][j][2] + bv);
                w4.w = f2bf(acc[i][j][3] + bv);
                *(ushort4*)&Vb[((size_t)((n * NH + h) * 32 + kb)) * 4096
                               + (((ct * 4 + dt) * 4 + quadv) * 16 + l15d) * 4] = w4;
            }
        }
    }
}

// ---------------- flash attention: 4 waves/q64-tile, 3-buffer LDS, counted vmcnt ----------------
// Round-0 compute structure (proven best: 12 waves/CU, global_load_lds staging,
// conflict-free lane-linear frag reads) with the barrier-drain stall removed:
//  - 3 LDS buffers (48KB -> still 3 blocks/CU at 160KB LDS)
//  - stage kb+2 right AFTER the barrier; at iter top wait s_waitcnt vmcnt(4)
//    (drains only kb's 4 staging loads; kb+1's 4 stay in flight across the raw
//    s_barrier — T3/T4 counted-vmcnt pattern; vmcnt(0) only at the last iter).
//    Safety: asm "memory" clobber + sched_barrier(0) pins ds_reads below the wait.
//  - XCD swizzle: bid&7 -> xcd handles nh in {xcd, xcd+8, xcd+16}: 1.5MB K+V
//    resident in the XCD's 4MB L2 -> staging at L2 BW, not L3.
//  - s_setprio(1) around both MFMA clusters (m191: attn-positive).
// Correctness of buffer rotation: at iter kb we stage into buf[(kb+2)%3] ==
// buf[(kb-1)%3], whose reads all completed before the barrier at iter kb.
__global__ __launch_bounds__(256) void attn_kernel(const unsigned short* __restrict__ Zq,
                                                   const unsigned short* __restrict__ Kb,
                                                   const unsigned short* __restrict__ Vb,
                                                   float* __restrict__ out) {
    __shared__ __attribute__((aligned(16))) unsigned short sK[3][4096];
    __shared__ __attribute__((aligned(16))) unsigned short sV[3][4096];
#if !HAVE_MFMA16
    __shared__ __attribute__((aligned(16))) unsigned short sP[4][16 * 72];
#endif

    const int tid  = threadIdx.x;
    const int wave = tid >> 6;
    const int lane = tid & 63;
    const int quad = lane >> 4;
    const int l15  = lane & 15;
    const int b    = blockIdx.x;
    const int xcd  = b & 7;
    const int ii   = b >> 3;            // 0..95
    const int t    = 31 - ii / 3;       // heavy-first q64-tile index
    const int nh   = (ii % 3) * 8 + xcd;
    const int n    = nh / NH;
    const int h    = nh - n * NH;

    const unsigned short* KbP = Kb + (size_t)(nh * 32) * 4096;
    const unsigned short* VbP = Vb + (size_t)(nh * 32) * 4096;

    // Q B-frags: lane holds Q[q = t*64+wave*16+l15][d = ks*32+quad*8..+7]
    const unsigned short* Qp = Zq + (size_t)(n * NCTX + t * 64 + wave * 16) * D_MODEL + h * HD;
    short8 qf[2];
#pragma unroll
    for (int ks = 0; ks < 2; ++ks)
        qf[ks] = *(const short8*)&Qp[(size_t)l15 * D_MODEL + ks * 32 + quad * 8];

    f32x4 o[4] = {};   // [dt]: O[q=quad*4+r][d=dt*16+l15]
    float lsum = 0.0f; // partial row-sum for q=l15

#define STAGE(kbi, bufi)                                                          \
    do {                                                                          \
        const size_t gof = (size_t)(kbi) * 4096;                                  \
        _Pragma("unroll")                                                         \
        for (int c = 0; c < 2; ++c) {                                             \
            const int off = wave * 1024 + c * 512;                                \
            async_copy16(KbP + gof + off + lane * 8, &sK[bufi][off]);             \
            async_copy16(VbP + gof + off + lane * 8, &sV[bufi][off]);             \
        }                                                                         \
    } while (0)

    // prologue: stage kb=0 and kb=1 (4 vmcnt items each per thread)
    STAGE(0, 0);
    if (t >= 1) STAGE(1, 1);

    int cb = 0;  // LDS buffer holding kb
    for (int kb = 0; kb <= t; ++kb) {
        // counted wait: kb's 4 staging loads done; kb+1's stay in flight
        if (kb == t) { asm volatile("s_waitcnt vmcnt(0)" ::: "memory"); }
        else         { asm volatile("s_waitcnt vmcnt(4)" ::: "memory"); }
        __builtin_amdgcn_s_barrier();
        __builtin_amdgcn_sched_barrier(0);

        if (kb + 2 <= t) {
            int nb = cb + 2; if (nb >= 3) nb -= 3;
            STAGE(kb + 2, nb);
        }

        // K A-frags: lane-linear, conflict-free
        short8 kf[2][4];
#pragma unroll
        for (int ks = 0; ks < 2; ++ks)
#pragma unroll
            for (int ct = 0; ct < 4; ++ct)
                kf[ks][ct] = *(const short8*)&sK[cb][(ks * 4 + ct) * 512 + lane * 8];

        // S^T = K Q^T: lane holds S[q=l15][key = kb*64 + ct*16 + quad*4 + r]
        f32x4 s[4] = {};
        __builtin_amdgcn_s_setprio(1);
#pragma unroll
        for (int ct = 0; ct < 4; ++ct) {
            s[ct] = __builtin_amdgcn_mfma_f32_16x16x32_bf16(kf[0][ct], qf[0], s[ct], 0, 0, 0);
            s[ct] = __builtin_amdgcn_mfma_f32_16x16x32_bf16(kf[1][ct], qf[1], s[ct], 0, 0, 0);
        }
        __builtin_amdgcn_s_setprio(0);

        const bool diag = (kb == t);
        const int qg = t * 64 + wave * 16 + l15;
#if HAVE_MFMA16
        bf16x4 pA[4];
#endif
#pragma unroll
        for (int ct = 0; ct < 4; ++ct) {
            float pv[4];
#pragma unroll
            for (int r = 0; r < 4; ++r) {
                const int key = kb * 64 + ct * 16 + quad * 4 + r;
                float sv = s[ct][r];
                if (diag && key > qg) sv = -INFINITY;
                pv[r] = fast_exp2(sv);
                lsum += pv[r];
            }
#if HAVE_MFMA16
            pA[ct][0] = (short)f2bf(pv[0]); pA[ct][1] = (short)f2bf(pv[1]);
            pA[ct][2] = (short)f2bf(pv[2]); pA[ct][3] = (short)f2bf(pv[3]);
#else
            ushort4 w4;
            w4.x = f2bf(pv[0]); w4.y = f2bf(pv[1]); w4.z = f2bf(pv[2]); w4.w = f2bf(pv[3]);
            *(ushort4*)&sP[wave][l15 * 72 + ct * 16 + quad * 4] = w4;
#endif
        }

        // O += P V
#if HAVE_MFMA16
        __builtin_amdgcn_s_setprio(1);
#pragma unroll
        for (int ct = 0; ct < 4; ++ct)
#pragma unroll
            for (int dt = 0; dt < 4; ++dt) {
                const bf16x4 vf = *(const bf16x4*)&sV[cb][(ct * 4 + dt) * 256 + lane * 4];
                o[dt] = __builtin_amdgcn_mfma_f32_16x16x16bf16_1k(pA[ct], vf, o[dt], 0, 0, 0);
            }
        __builtin_amdgcn_s_setprio(0);
#else
        // fallback: sP round-trip + x32 (V consumed as x16-blocked pairs)
        const short8 pf0 = *(const short8*)&sP[wave][l15 * 72 + quad * 8];
        const short8 pf1 = *(const short8*)&sP[wave][l15 * 72 + 32 + quad * 8];
#pragma unroll
        for (int dt = 0; dt < 4; ++dt) {
            short8 vf0, vf1;
#pragma unroll
            for (int e = 0; e < 8; ++e) {
                const int k0 = quad * 8 + e;          // within keys [0,32)
                const int k1 = 32 + quad * 8 + e;
                vf0[e] = (short)sV[cb][(((k0 >> 4) * 4 + dt) * 4 + ((k0 >> 2) & 3)) * 64 + l15 * 4 + (k0 & 3)];
                vf1[e] = (short)sV[cb][(((k1 >> 4) * 4 + dt) * 4 + ((k1 >> 2) & 3)) * 64 + l15 * 4 + (k1 & 3)];
            }
            o[dt] = __builtin_amdgcn_mfma_f32_16x16x32_bf16(pf0, vf0, o[dt], 0, 0, 0);
            o[dt] = __builtin_amdgcn_mfma_f32_16x16x32_bf16(pf1, vf1, o[dt], 0, 0, 0);
        }
#endif
        cb = (cb + 1 == 3) ? 0 : cb + 1;
    }
#undef STAGE

    // epilogue: full row-sum for q=l15 (reduce across quads), normalize, store
    float l = lsum;
    l += __shfl_xor(l, 16);
    l += __shfl_xor(l, 32);
    const float linv = 1.0f / l;                      // valid for q=l15
#pragma unroll
    for (int r = 0; r < 4; ++r) {
        const float inv = __shfl(linv, quad * 4 + r); // source lane's l15 == output q row
        const size_t row = (size_t)n * NCTX + t * 64 + wave * 16 + quad * 4 + r;
#pragma unroll
        for (int dt = 0; dt < 4; ++dt)
            out[row * D_MODEL + h * HD + dt * 16 + l15] = o[dt][r] * inv;
    }
}

extern "C" void kernel_launch(void* const* d_in, const int* in_sizes, int n_in,
                              void* d_out, int out_size, void* d_ws, size_t ws_size,
                              hipStream_t stream) {
    const float* x = (const float*)d_in[0];   // [2,2048,768]
    const float* W = (const float*)d_in[1];   // [2304,768]
    const float* b = (const float*)d_in[2];   // [2304]
    float* out = (float*)d_out;

    unsigned short* xb = (unsigned short*)d_ws;                    // 4096*768
    unsigned short* Wb = xb + (size_t)MROWS * D_MODEL;             // 2304*768
    unsigned short* Zq = Wb + (size_t)E3 * D_MODEL;                // 4096*768 (Q only)
    unsigned short* Kb = Zq + (size_t)MROWS * D_MODEL;             // 24*32*4096
    unsigned short* Vb = Kb + (size_t)NHTOT * 32 * 4096;           // 24*32*4096

    const int NA4 = MROWS * D_MODEL / 4;   // 786432 float4s (multiple of 256)
    const int NW4 = E3 * D_MODEL / 4;      // 442368 float4s
    cast2_bf16_kernel<<<dim3((NA4 + NW4) / 256), 256, 0, stream>>>(x, xb, NA4, W, Wb);
    qkv_gemm<<<dim3(E3 / 128, MROWS / 128), 256, 0, stream>>>(xb, Wb, b, Zq, Kb, Vb);
    attn_kernel<<<dim3(NHTOT * (NCTX / 64)), 256, 0, stream>>>(Zq, Kb, Vb, out);
}

// Round 4
// 140.477 us; speedup vs baseline: 1.6057x; 1.0898x over previous
//
#include <hip/hip_runtime.h>
#include <stdint.h>

#define D_MODEL 768
#define E3      2304
#define NCTX    2048
#define NH      12
#define HD      64
#define MROWS   4096  // 2*2048
#define NHTOT   24    // 2*12

typedef __attribute__((ext_vector_type(8))) short short8;   // 8 bf16 — MFMA x32 A/B frag
typedef __attribute__((ext_vector_type(4))) short bf16x4;   // 4 bf16 — MFMA x16 A/B frag
typedef __attribute__((ext_vector_type(4))) float f32x4;    // MFMA C/D frag

typedef __attribute__((address_space(3))) uint32_t lds_u32;
typedef __attribute__((address_space(1))) uint32_t glob_u32;

__device__ __forceinline__ void async_copy16(const void* g, void* l) {
    __builtin_amdgcn_global_load_lds((const glob_u32*)(uintptr_t)g,
                                     (lds_u32*)(uint32_t)(uintptr_t)l, 16, 0, 0);
}

__device__ __forceinline__ unsigned short f2bf(float f) {  // RNE fp32->bf16
    uint32_t u = __builtin_bit_cast(uint32_t, f);
    u += 0x7fffu + ((u >> 16) & 1u);
    return (unsigned short)(u >> 16);
}

__device__ __forceinline__ float fast_exp2(float x) {
#if __has_builtin(__builtin_amdgcn_exp2f)
    return __builtin_amdgcn_exp2f(x);
#else
    return __expf(x * 0.6931471805599453f);
#endif
}

#if __has_builtin(__builtin_amdgcn_mfma_f32_16x16x16bf16_1k)
#define HAVE_MFMA16 1
#else
#define HAVE_MFMA16 0
#endif

// ---------------- fused cast fp32 -> bf16 (x and W in one dispatch) ----------------
__global__ __launch_bounds__(256) void cast2_bf16_kernel(const float* __restrict__ a,
                                                         unsigned short* __restrict__ oa,
                                                         int na4,
                                                         const float* __restrict__ b,
                                                         unsigned short* __restrict__ ob) {
    int i = blockIdx.x * blockDim.x + threadIdx.x;
    const float4* src;
    ushort4* dst;
    int idx;
    if (i < na4) { src = (const float4*)a; dst = (ushort4*)oa; idx = i; }
    else         { src = (const float4*)b; dst = (ushort4*)ob; idx = i - na4; }
    float4 v = src[idx];
    ushort4 o;
    o.x = f2bf(v.x); o.y = f2bf(v.y); o.z = f2bf(v.z); o.w = f2bf(v.w);
    dst[idx] = o;
}

// ---------------- QKV GEMM, BK=64 (unchanged — at 128^2 structure ceiling) ----------------
// Outputs (all bf16):
//  Q -> Zq[4096][768], scaled by log2e/sqrt(768)
//  K -> Kb blocked: per (nh,kb64): elem (((ks*4+ct)*4+quadd)*16+l15k)*8+e
//       where d=ks*32+quadd*8+e, key%64=ct*16+l15k  (lane-linear for attn LDS frags)
//  V -> Vb blocked: per (nh,kb64): elem (((ct*4+dt)*4+quadv)*16+l15d)*4+e
//       where key%64=ct*16+quadv*4+e, d=dt*16+l15d
__global__ __launch_bounds__(256) void qkv_gemm(const unsigned short* __restrict__ A,
                                                const unsigned short* __restrict__ B,
                                                const float* __restrict__ bias,
                                                unsigned short* __restrict__ Zq,
                                                unsigned short* __restrict__ Kb,
                                                unsigned short* __restrict__ Vb) {
    __shared__ __attribute__((aligned(16))) unsigned short sA[128 * 64];
    __shared__ __attribute__((aligned(16))) unsigned short sB[128 * 64];

    const int tid  = threadIdx.x;
    const int wave = tid >> 6;
    const int lane = tid & 63;
    const int quad = lane >> 4;
    const int l15  = lane & 15;
    const int wm   = (wave >> 1) << 6;
    const int wn   = (wave & 1) << 6;
    const int row0 = blockIdx.y * 128;
    const int col0 = blockIdx.x * 128;

    const int srow   = lane >> 3;        // 0..7
    const int schunk = (lane & 7) * 8;   // elem offset within 64-elem row

    f32x4 acc[4][4] = {};

    for (int k0 = 0; k0 < D_MODEL; k0 += 64) {
        __syncthreads();
#pragma unroll
        for (int c = 0; c < 4; ++c) {    // 8-row chunks; 4 per wave per matrix
            const int rbase = wave * 32 + c * 8;
            async_copy16(A + (size_t)(row0 + rbase + srow) * D_MODEL + k0 + schunk, &sA[rbase * 64]);
            async_copy16(B + (size_t)(col0 + rbase + srow) * D_MODEL + k0 + schunk, &sB[rbase * 64]);
        }
        __syncthreads();

#pragma unroll
        for (int ks = 0; ks < 2; ++ks) {
            short8 aF[4], bF[4];
#pragma unroll
            for (int i = 0; i < 4; ++i)
                aF[i] = *(const short8*)&sA[(wm + i * 16 + l15) * 64 + ks * 32 + quad * 8];
#pragma unroll
            for (int i = 0; i < 4; ++i)
                bF[i] = *(const short8*)&sB[(wn + i * 16 + l15) * 64 + ks * 32 + quad * 8];
#pragma unroll
            for (int i = 0; i < 4; ++i)
#pragma unroll
                for (int j = 0; j < 4; ++j)
                    acc[i][j] = __builtin_amdgcn_mfma_f32_16x16x32_bf16(aF[i], bF[j], acc[i][j], 0, 0, 0);
        }
    }

    // epilogue: C/D layout col=lane&15 (j dim), row=quad*4+reg (i dim)
    if (col0 < D_MODEL) {
        // ---- K -> Kb blocked ----
#pragma unroll
        for (int j = 0; j < 4; ++j) {
            const int col = col0 + wn + j * 16 + l15;
            const float bv = bias[col];
            const int h = col >> 6, d = col & 63;
            const int ks = d >> 5, quadd = (d >> 3) & 3, e = d & 7;
#pragma unroll
            for (int i = 0; i < 4; ++i) {
                const int row = row0 + wm + i * 16 + quad * 4;   // +r
                const int n = row >> 11;
                const int key = row & (NCTX - 1);
                const int kb = key >> 6;
                const int ct = i;                                 // key%64 = i*16 + quad*4 + r
                const size_t base = ((size_t)((n * NH + h) * 32 + kb)) * 4096
                                  + (((ks * 4 + ct) * 4 + quadd) * 16) * 8 + e;
#pragma unroll
                for (int r = 0; r < 4; ++r)
                    Kb[base + (size_t)(quad * 4 + r) * 8] = f2bf(acc[i][j][r] + bv);
            }
        }
    } else if (col0 < 2 * D_MODEL) {
        // ---- Q -> Zq (scaled) ----
        const float zscale = 0.036084391824351615f * 1.4426950408889634f;
#pragma unroll
        for (int j = 0; j < 4; ++j) {
            const int col = col0 - D_MODEL + wn + j * 16 + l15;
            const float bv = bias[col0 + wn + j * 16 + l15];
#pragma unroll
            for (int i = 0; i < 4; ++i) {
                const int row = row0 + wm + i * 16 + quad * 4;
#pragma unroll
                for (int r = 0; r < 4; ++r)
                    Zq[(size_t)(row + r) * D_MODEL + col] = f2bf((acc[i][j][r] + bv) * zscale);
            }
        }
    } else {
        // ---- V -> Vb blocked (ushort4 over r: e=key&3) ----
#pragma unroll
        for (int j = 0; j < 4; ++j) {
            const int col = col0 + wn + j * 16 + l15;
            const float bv = bias[col];
            const int ch = col - 2 * D_MODEL;
            const int h = ch >> 6, d = ch & 63;
            const int dt = d >> 4, l15d = d & 15;
#pragma unroll
            for (int i = 0; i < 4; ++i) {
                const int row = row0 + wm + i * 16 + quad * 4;    // key base, %4==0
                const int n = row >> 11;
                const int key = row & (NCTX - 1);
                const int kb = key >> 6;
                const int ct = i, quadv = quad;
                ushort4 w4;
                w4.x = f2bf(acc[i][j][0] + bv);
                w4.y = f2bf(acc[i][j][1] + bv);
                w4.z = f2bf(acc[i][j][2] + bv);
                w4.w = f2bf(acc[i][j][3] + bv);
                *(ushort4*)&Vb[((size_t)((n * NH + h) * 32 + kb)) * 4096
                               + (((ct * 4 + dt) * 4 + quadv) * 16 + l15d) * 4] = w4;
            }
        }
    }
}

// ---------------- flash attention: 8-wave blocks, intra-block split-K ----------------
// Round-0 loop body EXACTLY (2-buf LDS, plain __syncthreads, no setprio/sched_barrier
// — r3's counted-vmcnt bundle regressed 40->46.5us). Structural change: block = 512
// threads; waves 0-3 (half 0) process the q64 tile against kb [0, nA), waves 4-7
// (half 1) against kb [nA, t+1) — DISJOINT ranges, so staging traffic is unchanged,
// and each half owns its own 2-buf LDS pair (64KB total -> 2 blocks/CU = 16 waves/CU,
// with 768 blocks = 3/CU giving a refill queue). Heaviest block: 16 iters (was 32).
// This attacks the measured tail: OccupancyPercent 15.6 vs 37.5 resident-peak.
// m == 0 fixed, so partials combine linearly: half-1 waves drop partial O + rowsums
// into LDS after the loop; half-0 waves add, normalize by lA+lB, store.
__global__ __launch_bounds__(512) void attn_kernel(const unsigned short* __restrict__ Zq,
                                                   const unsigned short* __restrict__ Kb,
                                                   const unsigned short* __restrict__ Vb,
                                                   float* __restrict__ out) {
    __shared__ __attribute__((aligned(16))) unsigned short sK[2][2][4096];  // [half][buf]
    __shared__ __attribute__((aligned(16))) unsigned short sV[2][2][4096];
#if !HAVE_MFMA16
    __shared__ __attribute__((aligned(16))) unsigned short sP[8][16 * 72];
#endif

    const int tid  = threadIdx.x;
    const int wave = tid >> 6;          // 0..7
    const int half = wave >> 2;         // 0: keys [0,nA), 1: keys [nA,t+1)
    const int wv   = wave & 3;          // q16 group within q64 tile
    const int lane = tid & 63;
    const int quad = lane >> 4;
    const int l15  = lane & 15;
    const int b    = blockIdx.x;
    const int xcd  = b & 7;
    const int ii   = b >> 3;            // 0..95
    const int t    = 31 - ii / 3;       // heavy-first q64-tile index
    const int nh   = (ii % 3) * 8 + xcd;
    const int n    = nh / NH;
    const int h    = nh - n * NH;

    const int nA    = (t + 2) >> 1;     // iterations for half 0 (>=1)
    const int nB    = t + 1 - nA;       // iterations for half 1 (nA or nA-1)
    const int kbase = half ? nA : 0;
    const int nMy   = half ? nB : nA;

    const unsigned short* KbP = Kb + (size_t)(nh * 32) * 4096;
    const unsigned short* VbP = Vb + (size_t)(nh * 32) * 4096;

    // Q B-frags: lane holds Q[q = t*64+wv*16+l15][d = ks*32+quad*8..+7]
    const unsigned short* Qp = Zq + (size_t)(n * NCTX + t * 64 + wv * 16) * D_MODEL + h * HD;
    short8 qf[2];
#pragma unroll
    for (int ks = 0; ks < 2; ++ks)
        qf[ks] = *(const short8*)&Qp[(size_t)l15 * D_MODEL + ks * 32 + quad * 8];

    f32x4 o[4] = {};   // [dt]: partial O[q=quad*4+r][d=dt*16+l15]
    float lsum = 0.0f; // partial row-sum for q=l15

    // Staging: per half, its 4 waves (wv 0..3) cover the full 8KB K + 8KB V block.
#define STAGE(kbi, bufi)                                                          \
    do {                                                                          \
        const size_t gof = (size_t)(kbi) * 4096;                                  \
        _Pragma("unroll")                                                         \
        for (int c = 0; c < 2; ++c) {                                             \
            const int off = wv * 1024 + c * 512;                                  \
            async_copy16(KbP + gof + off + lane * 8, &sK[half][bufi][off]);       \
            async_copy16(VbP + gof + off + lane * 8, &sV[half][bufi][off]);       \
        }                                                                         \
    } while (0)

    if (nMy > 0) STAGE(kbase, 0);

    for (int i = 0; i < nA; ++i) {       // nA >= nB: uniform barrier count
        __syncthreads();                 // drains staging of iter i; frees buf^1
        if (i + 1 < nMy) STAGE(kbase + i + 1, (i + 1) & 1);

        if (i < nMy) {
            const int kb  = kbase + i;
            const int buf = i & 1;

            // K A-frags: lane-linear, conflict-free
            short8 kf[2][4];
#pragma unroll
            for (int ks = 0; ks < 2; ++ks)
#pragma unroll
                for (int ct = 0; ct < 4; ++ct)
                    kf[ks][ct] = *(const short8*)&sK[half][buf][(ks * 4 + ct) * 512 + lane * 8];

            // S^T = K Q^T: lane holds S[q=l15][key = kb*64 + ct*16 + quad*4 + r]
            f32x4 s[4] = {};
#pragma unroll
            for (int ct = 0; ct < 4; ++ct) {
                s[ct] = __builtin_amdgcn_mfma_f32_16x16x32_bf16(kf[0][ct], qf[0], s[ct], 0, 0, 0);
                s[ct] = __builtin_amdgcn_mfma_f32_16x16x32_bf16(kf[1][ct], qf[1], s[ct], 0, 0, 0);
            }

            const bool diag = (kb == t);
            const int qg = t * 64 + wv * 16 + l15;
#if HAVE_MFMA16
            bf16x4 pA[4];
#endif
#pragma unroll
            for (int ct = 0; ct < 4; ++ct) {
                float pv[4];
#pragma unroll
                for (int r = 0; r < 4; ++r) {
                    const int key = kb * 64 + ct * 16 + quad * 4 + r;
                    float sv = s[ct][r];
                    if (diag && key > qg) sv = -INFINITY;
                    pv[r] = fast_exp2(sv);
                    lsum += pv[r];
                }
#if HAVE_MFMA16
                pA[ct][0] = (short)f2bf(pv[0]); pA[ct][1] = (short)f2bf(pv[1]);
                pA[ct][2] = (short)f2bf(pv[2]); pA[ct][3] = (short)f2bf(pv[3]);
#else
                ushort4 w4;
                w4.x = f2bf(pv[0]); w4.y = f2bf(pv[1]); w4.z = f2bf(pv[2]); w4.w = f2bf(pv[3]);
                *(ushort4*)&sP[wave][l15 * 72 + ct * 16 + quad * 4] = w4;
#endif
            }

            // O += P V
#if HAVE_MFMA16
#pragma unroll
            for (int ct = 0; ct < 4; ++ct)
#pragma unroll
                for (int dt = 0; dt < 4; ++dt) {
                    const bf16x4 vf = *(const bf16x4*)&sV[half][buf][(ct * 4 + dt) * 256 + lane * 4];
                    o[dt] = __builtin_amdgcn_mfma_f32_16x16x16bf16_1k(pA[ct], vf, o[dt], 0, 0, 0);
                }
#else
            // fallback: sP round-trip + x32 (V consumed as x16-blocked pairs)
            const short8 pf0 = *(const short8*)&sP[wave][l15 * 72 + quad * 8];
            const short8 pf1 = *(const short8*)&sP[wave][l15 * 72 + 32 + quad * 8];
#pragma unroll
            for (int dt = 0; dt < 4; ++dt) {
                short8 vf0, vf1;
#pragma unroll
                for (int e = 0; e < 8; ++e) {
                    const int k0 = quad * 8 + e;          // within keys [0,32)
                    const int k1 = 32 + quad * 8 + e;
                    vf0[e] = (short)sV[half][buf][(((k0 >> 4) * 4 + dt) * 4 + ((k0 >> 2) & 3)) * 64 + l15 * 4 + (k0 & 3)];
                    vf1[e] = (short)sV[half][buf][(((k1 >> 4) * 4 + dt) * 4 + ((k1 >> 2) & 3)) * 64 + l15 * 4 + (k1 & 3)];
                }
                o[dt] = __builtin_amdgcn_mfma_f32_16x16x32_bf16(pf0, vf0, o[dt], 0, 0, 0);
                o[dt] = __builtin_amdgcn_mfma_f32_16x16x32_bf16(pf1, vf1, o[dt], 0, 0, 0);
            }
#endif
        }
    }
#undef STAGE

    // partial row-sum reduce across quads: every lane with index l15 holds this
    // half's full sum for q row l15
    float l = lsum;
    l += __shfl_xor(l, 16);
    l += __shfl_xor(l, 32);

    // ---- combine halves via LDS (reuses sK region; 4 waves x 1040 floats = 16.6KB) ----
    __syncthreads();                       // all loop reads of sK/sV done
    float* red = (float*)&sK[0][0][0];
    if (half == 1) {
        float* po = red + wv * 1040;
#pragma unroll
        for (int dt = 0; dt < 4; ++dt)
#pragma unroll
            for (int r = 0; r < 4; ++r)
                po[(quad * 4 + r) * 64 + dt * 16 + l15] = o[dt][r];
        if (quad == 0) po[1024 + l15] = l;
    }
    __syncthreads();
    if (half == 0) {
        const float* po = red + wv * 1040;
        const float l2 = po[1024 + l15];                  // broadcast read
        const float linv = 1.0f / (l + l2);               // valid for q=l15
#pragma unroll
        for (int r = 0; r < 4; ++r) {
            const float inv = __shfl(linv, quad * 4 + r); // source lane's l15 == output q row
            const size_t row = (size_t)n * NCTX + t * 64 + wv * 16 + quad * 4 + r;
#pragma unroll
            for (int dt = 0; dt < 4; ++dt)
                out[row * D_MODEL + h * HD + dt * 16 + l15] =
                    (o[dt][r] + po[(quad * 4 + r) * 64 + dt * 16 + l15]) * inv;
        }
    }
}

extern "C" void kernel_launch(void* const* d_in, const int* in_sizes, int n_in,
                              void* d_out, int out_size, void* d_ws, size_t ws_size,
                              hipStream_t stream) {
    const float* x = (const float*)d_in[0];   // [2,2048,768]
    const float* W = (const float*)d_in[1];   // [2304,768]
    const float* b = (const float*)d_in[2];   // [2304]
    float* out = (float*)d_out;

    unsigned short* xb = (unsigned short*)d_ws;                    // 4096*768
    unsigned short* Wb = xb + (size_t)MROWS * D_MODEL;             // 2304*768
    unsigned short* Zq = Wb + (size_t)E3 * D_MODEL;                // 4096*768 (Q only)
    unsigned short* Kb = Zq + (size_t)MROWS * D_MODEL;             // 24*32*4096
    unsigned short* Vb = Kb + (size_t)NHTOT * 32 * 4096;           // 24*32*4096

    const int NA4 = MROWS * D_MODEL / 4;   // 786432 float4s (multiple of 256)
    const int NW4 = E3 * D_MODEL / 4;      // 442368 float4s
    cast2_bf16_kernel<<<dim3((NA4 + NW4) / 256), 256, 0, stream>>>(x, xb, NA4, W, Wb);
    qkv_gemm<<<dim3(E3 / 128, MROWS / 128), 256, 0, stream>>>(xb, Wb, b, Zq, Kb, Vb);
    attn_kernel<<<dim3(NHTOT * (NCTX / 64)), 512, 0, stream>>>(Zq, Kb, Vb, out);
}